// Round 12
// baseline (24.209 us; speedup 1.0000x reference)
//
#include <hip/hip_runtime.h>

#define LPTS  2048   // points per row
#define NSEG  2047   // increments per row
#define TPB   256
#define STEPS 8      // segments per thread
#define NBATCH 2048
#define ROWS  2      // rows per block
#define GRIDN (NBATCH / ROWS)
#define NWAVE (TPB / 64)

// DPP lane-shift returning 0 for lanes without a source (bound_ctrl) or in
// masked-off rows (row_mask). Zero state == identity for chen_combine7.
template <int CTRL, int RMASK, bool BC>
__device__ __forceinline__ float dpp_f(float s) {
    return __int_as_float(__builtin_amdgcn_update_dpp(
        0, __float_as_int(s), CTRL, RMASK, 0xF, BC));
}

// Quotient signature state (7 floats): s[0]=a1x s[1]=a1y s[2]=a2xx s[3]=a2xy
// s[4]=a2yx s[5]=a2yy s[6]=z3 (= <WO3, a3>).

__device__ __forceinline__ void chen_step7(float s[7], float vx, float vy,
                                           const float WO[14], float WO78,
                                           float WO1112) {
    const float qxx = 0.5f * vx * vx;
    const float qxy = 0.5f * vx * vy;
    const float qyy = 0.5f * vy * vy;
    const float wx = fmaf(vx, (1.0f / 3.0f), s[0]);
    const float wy = fmaf(vy, (1.0f / 3.0f), s[1]);
    const float tvxx = fmaf(WO[7], vy, WO[6] * vx);
    const float tvxy = fmaf(WO[9], vy, WO[8] * vx);
    const float tvyx = fmaf(WO[11], vy, WO[10] * vx);
    const float tvyy = fmaf(WO[13], vy, WO[12] * vx);
    const float tqx = fmaf(WO[9], qyy, fmaf(WO78, qxy, WO[6] * qxx));
    const float tqy = fmaf(WO[13], qyy, fmaf(WO1112, qxy, WO[10] * qxx));
    float z1 = fmaf(s[2], tvxx, s[6]);
    z1 = fmaf(s[4], tvyx, z1);
    z1 = fmaf(wx, tqx, z1);
    float z2 = fmaf(s[5], tvyy, s[3] * tvxy);
    z2 = fmaf(wy, tqy, z2);
    s[6] = z1 + z2;
    const float ux = fmaf(vx, 0.5f, s[0]);
    const float uy = fmaf(vy, 0.5f, s[1]);
    s[2] = fmaf(ux, vx, s[2]);
    s[3] = fmaf(ux, vy, s[3]);
    s[4] = fmaf(uy, vx, s[4]);
    s[5] = fmaf(uy, vy, s[5]);
    s[0] += vx;
    s[1] += vy;
}

// b := a ⊗ b (a earlier). a == zeros is identity.
__device__ __forceinline__ void chen_combine7(const float a[7], float b[7],
                                              const float WO[14]) {
    const float tvxx = fmaf(WO[7], b[1], WO[6] * b[0]);
    const float tvxy = fmaf(WO[9], b[1], WO[8] * b[0]);
    const float tvyx = fmaf(WO[11], b[1], WO[10] * b[0]);
    const float tvyy = fmaf(WO[13], b[1], WO[12] * b[0]);
    const float ubx = fmaf(WO[9], b[5], fmaf(WO[8], b[4], fmaf(WO[7], b[3], WO[6] * b[2])));
    const float uby = fmaf(WO[13], b[5], fmaf(WO[12], b[4], fmaf(WO[11], b[3], WO[10] * b[2])));
    float z1 = fmaf(a[2], tvxx, a[6] + b[6]);
    z1 = fmaf(a[4], tvyx, z1);
    z1 = fmaf(a[0], ubx, z1);
    float z2 = fmaf(a[5], tvyy, a[3] * tvxy);
    z2 = fmaf(a[1], uby, z2);
    const float cxx = a[2] + fmaf(a[0], b[0], b[2]);
    const float cxy = a[3] + fmaf(a[0], b[1], b[3]);
    const float cyx = a[4] + fmaf(a[1], b[0], b[4]);
    const float cyy = a[5] + fmaf(a[1], b[1], b[5]);
    b[0] = a[0] + b[0];
    b[1] = a[1] + b[1];
    b[2] = cxx;
    b[3] = cxy;
    b[4] = cyx;
    b[5] = cyy;
    b[6] = z1 + z2;
}

// pointwise MLP 1 -> 8 -> 2 (ReLU between)
__device__ __forceinline__ void augment(float x,
                                        const float W1[8], const float B1[8],
                                        const float W2x[8], const float W2y[8],
                                        float B2x, float B2y,
                                        float& px, float& py) {
    float ox = B2x, oy = B2y;
#pragma unroll
    for (int c = 0; c < 8; ++c) {
        float h = fmaxf(fmaf(W1[c], x, B1[c]), 0.0f);
        ox = fmaf(W2x[c], h, ox);
        oy = fmaf(W2y[c], h, oy);
    }
    px = ox;
    py = oy;
}

#define SCAN_ROUND(CTRL, RMASK, BC)                                      \
    {                                                                    \
        float p[7];                                                      \
        _Pragma("unroll")                                                \
        for (int i = 0; i < 7; ++i) p[i] = dpp_f<CTRL, RMASK, BC>(s[i]); \
        chen_combine7(p, s, WO);                                         \
    }

__global__ __launch_bounds__(TPB, 4) void sig_scan_kernel(
    const float* __restrict__ x, const float* __restrict__ w1,
    const float* __restrict__ b1, const float* __restrict__ w2,
    const float* __restrict__ b2, const float* __restrict__ wout,
    float* __restrict__ out) {
    __shared__ float wsum[2][NWAVE][8];  // double-buffered by row parity

    const int t = threadIdx.x;
    const int lane = t & 63;
    const int wv = t >> 6;

    // uniform weights loaded ONCE per block (s_load), reused across ROWS rows
    float W1[8], B1[8], W2x[8], W2y[8];
#pragma unroll
    for (int c = 0; c < 8; ++c) {
        W1[c] = w1[c];
        B1[c] = b1[c];
        W2x[c] = w2[c];
        W2y[c] = w2[8 + c];
    }
    const float B2x = b2[0], B2y = b2[1];
    float WO[14];
#pragma unroll
    for (int i = 0; i < 14; ++i) WO[i] = wout[i];
    const float WO78 = WO[7] + WO[8];
    const float WO1112 = WO[11] + WO[12];

    for (int r = 0; r < ROWS; ++r) {
        const int brow = blockIdx.x + r * GRIDN;
        const float* __restrict__ xrow = x + (size_t)brow * LPTS;

        // ---- phase 1: load 9 points, augment, two independent 4-step chains ----
        const int n0 = t * STEPS;
        const float4 xa = *reinterpret_cast<const float4*>(xrow + n0);
        const float4 xb = *reinterpret_cast<const float4*>(xrow + n0 + 4);
        const int ib = (n0 + STEPS > LPTS - 1) ? (LPTS - 1) : (n0 + STEPS);
        const float x8 = xrow[ib];  // clamped -> v=0 identity for last thread
        const float xv[STEPS + 1] = {xa.x, xa.y, xa.z, xa.w,
                                     xb.x, xb.y, xb.z, xb.w, x8};

        float vx[STEPS], vy[STEPS];
        {
            float ppx, ppy;
            augment(xv[0], W1, B1, W2x, W2y, B2x, B2y, ppx, ppy);
#pragma unroll
            for (int k = 0; k < STEPS; ++k) {
                float px, py;
                augment(xv[k + 1], W1, B1, W2x, W2y, B2x, B2y, px, py);
                vx[k] = px - ppx;
                vy[k] = py - ppy;
                ppx = px;
                ppy = py;
            }
        }
        float s_lo[7] = {0, 0, 0, 0, 0, 0, 0};  // sig of segments 0..3
        float s[7] = {0, 0, 0, 0, 0, 0, 0};     // sig of segments 4..7, then whole
#pragma unroll
        for (int k = 0; k < 4; ++k) {           // two independent chains -> 2x ILP
            chen_step7(s_lo, vx[k], vy[k], WO, WO78, WO1112);
            chen_step7(s, vx[k + 4], vy[k + 4], WO, WO78, WO1112);
        }
        chen_combine7(s_lo, s, WO);             // s = s_lo ⊗ s_hi

        // ---- phase 2a: wave64 inclusive scan, pure DPP ----
        SCAN_ROUND(0x111, 0xF, true)   // row_shr:1
        SCAN_ROUND(0x112, 0xF, true)   // row_shr:2
        SCAN_ROUND(0x114, 0xF, true)   // row_shr:4
        SCAN_ROUND(0x118, 0xF, true)   // row_shr:8
        SCAN_ROUND(0x142, 0xA, false)  // row_bcast15 -> rows 1,3
        SCAN_ROUND(0x143, 0xC, false)  // row_bcast31 -> rows 2,3

        // ---- phase 2b: cross-wave combine (one barrier) ----
        if (lane == 63) {
#pragma unroll
            for (int i = 0; i < 7; ++i) wsum[r & 1][wv][i] = s[i];
        }
        __syncthreads();

        float a[7];  // exclusive carry
#pragma unroll
        for (int i = 0; i < 7; ++i) a[i] = dpp_f<0x138, 0xF, true>(s[i]);
        for (int w = wv - 1; w >= 0; --w) {
            float tw[7];
#pragma unroll
            for (int i = 0; i < 7; ++i) tw[i] = wsum[r & 1][w][i];
            chen_combine7(tw, a, WO);
        }

        // ---- phase 3: two independent replay chains (2x ILP) ----
        float a_hi[7];
#pragma unroll
        for (int i = 0; i < 7; ++i) a_hi[i] = s_lo[i];
        chen_combine7(a, a_hi, WO);  // a_hi = a ⊗ sig(seg 0..3)

        float* __restrict__ orow = out + (size_t)brow * NSEG;
        float og[STEPS];
#pragma unroll
        for (int k = 0; k < 4; ++k) {
            chen_step7(a, vx[k], vy[k], WO, WO78, WO1112);
            float o = a[6];
            o = fmaf(WO[0], a[0], o);
            o = fmaf(WO[1], a[1], o);
            o = fmaf(WO[2], a[2], o);
            o = fmaf(WO[3], a[3], o);
            o = fmaf(WO[4], a[4], o);
            o = fmaf(WO[5], a[5], o);
            og[k] = o;
            chen_step7(a_hi, vx[k + 4], vy[k + 4], WO, WO78, WO1112);
            float o2 = a_hi[6];
            o2 = fmaf(WO[0], a_hi[0], o2);
            o2 = fmaf(WO[1], a_hi[1], o2);
            o2 = fmaf(WO[2], a_hi[2], o2);
            o2 = fmaf(WO[3], a_hi[3], o2);
            o2 = fmaf(WO[4], a_hi[4], o2);
            o2 = fmaf(WO[5], a_hi[5], o2);
            og[k + 4] = o2;
        }
#pragma unroll
        for (int k = 0; k < STEPS; ++k) {
            const int n = n0 + k;
            if (n < NSEG) orow[n] = og[k];
        }
    }
}

extern "C" void kernel_launch(void* const* d_in, const int* in_sizes, int n_in,
                              void* d_out, int out_size, void* d_ws, size_t ws_size,
                              hipStream_t stream) {
    const float* x  = (const float*)d_in[0];
    const float* w1 = (const float*)d_in[1];
    const float* b1 = (const float*)d_in[2];
    const float* w2 = (const float*)d_in[3];
    const float* b2 = (const float*)d_in[4];
    const float* wo = (const float*)d_in[5];
    float* out = (float*)d_out;
    sig_scan_kernel<<<GRIDN, TPB, 0, stream>>>(x, w1, b1, w2, b2, wo, out);
}

// Round 13
// 19.727 us; speedup vs baseline: 1.2272x; 1.2272x over previous
//
#include <hip/hip_runtime.h>

#define LPTS  2048   // points per row
#define NSEG  2047   // increments per row
#define TPB   256
#define STEPS 8      // segments per thread
#define NBATCH 2048
#define NWAVE (TPB / 64)

// DPP lane-shift returning 0 for lanes without a source (bound_ctrl) or in
// masked-off rows (row_mask). Zero == identity for all our combines.
template <int CTRL, int RMASK, bool BC>
__device__ __forceinline__ float dpp_f(float s) {
    return __int_as_float(__builtin_amdgcn_update_dpp(
        0, __float_as_int(s), CTRL, RMASK, 0xF, BC));
}

// Quotient signature state (7 floats): s[0]=a1x s[1]=a1y s[2]=a2xx s[3]=a2xy
// s[4]=a2yx s[5]=a2yy s[6]=z3 (= <WO3, a3>).

__device__ __forceinline__ void chen_step7(float s[7], float vx, float vy,
                                           const float WO[14], float WO78,
                                           float WO1112) {
    const float qxx = 0.5f * vx * vx;
    const float qxy = 0.5f * vx * vy;
    const float qyy = 0.5f * vy * vy;
    const float wx = fmaf(vx, (1.0f / 3.0f), s[0]);
    const float wy = fmaf(vy, (1.0f / 3.0f), s[1]);
    const float tvxx = fmaf(WO[7], vy, WO[6] * vx);
    const float tvxy = fmaf(WO[9], vy, WO[8] * vx);
    const float tvyx = fmaf(WO[11], vy, WO[10] * vx);
    const float tvyy = fmaf(WO[13], vy, WO[12] * vx);
    const float tqx = fmaf(WO[9], qyy, fmaf(WO78, qxy, WO[6] * qxx));
    const float tqy = fmaf(WO[13], qyy, fmaf(WO1112, qxy, WO[10] * qxx));
    float z1 = fmaf(s[2], tvxx, s[6]);
    z1 = fmaf(s[4], tvyx, z1);
    z1 = fmaf(wx, tqx, z1);
    float z2 = fmaf(s[5], tvyy, s[3] * tvxy);
    z2 = fmaf(wy, tqy, z2);
    s[6] = z1 + z2;
    const float ux = fmaf(vx, 0.5f, s[0]);
    const float uy = fmaf(vy, 0.5f, s[1]);
    s[2] = fmaf(ux, vx, s[2]);
    s[3] = fmaf(ux, vy, s[3]);
    s[4] = fmaf(uy, vx, s[4]);
    s[5] = fmaf(uy, vy, s[5]);
    s[0] += vx;
    s[1] += vy;
}

// Full 7-state combine (used only for cross-wave carry stitching).
__device__ __forceinline__ void chen_combine7(const float a[7], float b[7],
                                              const float WO[14]) {
    const float tvxx = fmaf(WO[7], b[1], WO[6] * b[0]);
    const float tvxy = fmaf(WO[9], b[1], WO[8] * b[0]);
    const float tvyx = fmaf(WO[11], b[1], WO[10] * b[0]);
    const float tvyy = fmaf(WO[13], b[1], WO[12] * b[0]);
    const float ubx = fmaf(WO[9], b[5], fmaf(WO[8], b[4], fmaf(WO[7], b[3], WO[6] * b[2])));
    const float uby = fmaf(WO[13], b[5], fmaf(WO[12], b[4], fmaf(WO[11], b[3], WO[10] * b[2])));
    float z1 = fmaf(a[2], tvxx, a[6] + b[6]);
    z1 = fmaf(a[4], tvyx, z1);
    z1 = fmaf(a[0], ubx, z1);
    float z2 = fmaf(a[5], tvyy, a[3] * tvxy);
    z2 = fmaf(a[1], uby, z2);
    const float cxx = a[2] + fmaf(a[0], b[0], b[2]);
    const float cxy = a[3] + fmaf(a[0], b[1], b[3]);
    const float cyx = a[4] + fmaf(a[1], b[0], b[4]);
    const float cyy = a[5] + fmaf(a[1], b[1], b[5]);
    b[0] = a[0] + b[0];
    b[1] = a[1] + b[1];
    b[2] = cxx;
    b[3] = cxy;
    b[4] = cyx;
    b[5] = cyy;
    b[6] = z1 + z2;
}

// Cheap 6-state combine (a1,a2 only — z deferred): b := a ⊗ b, 10 ops.
__device__ __forceinline__ void chen_combine6(const float a[6], float b[6]) {
    const float cxx = a[2] + fmaf(a[0], b[0], b[2]);
    const float cxy = a[3] + fmaf(a[0], b[1], b[3]);
    const float cyx = a[4] + fmaf(a[1], b[0], b[4]);
    const float cyy = a[5] + fmaf(a[1], b[1], b[5]);
    b[0] = a[0] + b[0];
    b[1] = a[1] + b[1];
    b[2] = cxx;
    b[3] = cxy;
    b[4] = cyx;
    b[5] = cyy;
}

// pointwise MLP 1 -> 8 -> 2 (ReLU between)
__device__ __forceinline__ void augment(float x,
                                        const float W1[8], const float B1[8],
                                        const float W2x[8], const float W2y[8],
                                        float B2x, float B2y,
                                        float& px, float& py) {
    float ox = B2x, oy = B2y;
#pragma unroll
    for (int c = 0; c < 8; ++c) {
        float h = fmaxf(fmaf(W1[c], x, B1[c]), 0.0f);
        ox = fmaf(W2x[c], h, ox);
        oy = fmaf(W2y[c], h, oy);
    }
    px = ox;
    py = oy;
}

#define SCAN6_ROUND(CTRL, RMASK, BC)                                     \
    {                                                                    \
        float p[6];                                                      \
        _Pragma("unroll")                                                \
        for (int i = 0; i < 6; ++i) p[i] = dpp_f<CTRL, RMASK, BC>(s[i]); \
        chen_combine6(p, s);                                             \
    }

#define USCAN_ROUND(CTRL, RMASK, BC) u += dpp_f<CTRL, RMASK, BC>(u);

__global__ void sig_scan_kernel(
    const float* __restrict__ x, const float* __restrict__ w1,
    const float* __restrict__ b1, const float* __restrict__ w2,
    const float* __restrict__ b2, const float* __restrict__ wout,
    float* __restrict__ out) {
    __shared__ float wsum[NWAVE][8];

    const int t = threadIdx.x;
    const int lane = t & 63;
    const int wv = t >> 6;
    const int brow = blockIdx.x;
    const float* __restrict__ xrow = x + (size_t)brow * LPTS;

    // uniform weights (uniform addresses -> s_load)
    float W1[8], B1[8], W2x[8], W2y[8];
#pragma unroll
    for (int c = 0; c < 8; ++c) {
        W1[c] = w1[c];
        B1[c] = b1[c];
        W2x[c] = w2[c];
        W2y[c] = w2[8 + c];
    }
    const float B2x = b2[0], B2y = b2[1];
    float WO[14];
#pragma unroll
    for (int i = 0; i < 14; ++i) WO[i] = wout[i];
    const float WO78 = WO[7] + WO[8];
    const float WO1112 = WO[11] + WO[12];

    // ---- phase 1: load 9 points, augment, increments, local 7-state sig ----
    const int n0 = t * STEPS;
    const float4 xa = *reinterpret_cast<const float4*>(xrow + n0);
    const float4 xb = *reinterpret_cast<const float4*>(xrow + n0 + 4);
    const int ib = (n0 + STEPS > LPTS - 1) ? (LPTS - 1) : (n0 + STEPS);
    const float x8 = xrow[ib];  // clamped -> v=0 identity for last thread
    const float xv[STEPS + 1] = {xa.x, xa.y, xa.z, xa.w,
                                 xb.x, xb.y, xb.z, xb.w, x8};

    float vx[STEPS], vy[STEPS];
    float s[7] = {0, 0, 0, 0, 0, 0, 0};
    float ppx, ppy;
    augment(xv[0], W1, B1, W2x, W2y, B2x, B2y, ppx, ppy);
#pragma unroll
    for (int k = 0; k < STEPS; ++k) {
        float px, py;
        augment(xv[k + 1], W1, B1, W2x, W2y, B2x, B2y, px, py);
        vx[k] = px - ppx;
        vy[k] = py - ppy;
        ppx = px;
        ppy = py;
        chen_step7(s, vx[k], vy[k], WO, WO78, WO1112);
    }

    // keep local chunk sig (scan overwrites s[0..5]); s[6]=zloc never scanned
    float sl[7];
#pragma unroll
    for (int i = 0; i < 7; ++i) sl[i] = s[i];

    // ---- phase 2a: wave64 inclusive 6-state DPP scan (z deferred) ----
    SCAN6_ROUND(0x111, 0xF, true)   // row_shr:1
    SCAN6_ROUND(0x112, 0xF, true)   // row_shr:2
    SCAN6_ROUND(0x114, 0xF, true)   // row_shr:4
    SCAN6_ROUND(0x118, 0xF, true)   // row_shr:8
    SCAN6_ROUND(0x142, 0xA, false)  // row_bcast15 -> rows 1,3
    SCAN6_ROUND(0x143, 0xC, false)  // row_bcast31 -> rows 2,3

    // exclusive 6-state carry (wave_shr:1, lane 0 -> identity)
    float e[6];
#pragma unroll
    for (int i = 0; i < 6; ++i) e[i] = dpp_f<0x138, 0xF, true>(s[i]);

    // per-lane z summand: u = zloc + <WO3, e_a2 (x) s1loc> + <WO3, e_a1 (x) a2loc>
    float u;
    {
        const float tvxx = fmaf(WO[7], sl[1], WO[6] * sl[0]);
        const float tvxy = fmaf(WO[9], sl[1], WO[8] * sl[0]);
        const float tvyx = fmaf(WO[11], sl[1], WO[10] * sl[0]);
        const float tvyy = fmaf(WO[13], sl[1], WO[12] * sl[0]);
        const float ubx = fmaf(WO[9], sl[5], fmaf(WO[8], sl[4], fmaf(WO[7], sl[3], WO[6] * sl[2])));
        const float uby = fmaf(WO[13], sl[5], fmaf(WO[12], sl[4], fmaf(WO[11], sl[3], WO[10] * sl[2])));
        u = fmaf(e[2], tvxx, sl[6]);
        u = fmaf(e[3], tvxy, u);
        u = fmaf(e[4], tvyx, u);
        u = fmaf(e[5], tvyy, u);
        u = fmaf(e[0], ubx, u);
        u = fmaf(e[1], uby, u);
    }

    // inclusive add-scan of u (cheap: 1 DPP + 1 add per round)
    USCAN_ROUND(0x111, 0xF, true)
    USCAN_ROUND(0x112, 0xF, true)
    USCAN_ROUND(0x114, 0xF, true)
    USCAN_ROUND(0x118, 0xF, true)
    USCAN_ROUND(0x142, 0xA, false)
    USCAN_ROUND(0x143, 0xC, false)

    // ---- phase 2b: cross-wave combine (one barrier, broadcast reads) ----
    if (lane == 63) {
#pragma unroll
        for (int i = 0; i < 6; ++i) wsum[wv][i] = s[i];
        wsum[wv][6] = u;  // wave z total
    }
    __syncthreads();

    float a[7];  // exclusive carry (wave-local)
#pragma unroll
    for (int i = 0; i < 6; ++i) a[i] = e[i];
    a[6] = dpp_f<0x138, 0xF, true>(u);  // exclusive z prefix
    for (int w = wv - 1; w >= 0; --w) {
        float tw[7];
#pragma unroll
        for (int i = 0; i < 7; ++i) tw[i] = wsum[w][i];
        chen_combine7(tw, a, WO);
    }

    // ---- phase 3: replay with carry, project, direct store ----
    float* __restrict__ orow = out + (size_t)brow * NSEG;
#pragma unroll
    for (int k = 0; k < STEPS; ++k) {
        chen_step7(a, vx[k], vy[k], WO, WO78, WO1112);
        float o = a[6];
        o = fmaf(WO[0], a[0], o);
        o = fmaf(WO[1], a[1], o);
        o = fmaf(WO[2], a[2], o);
        o = fmaf(WO[3], a[3], o);
        o = fmaf(WO[4], a[4], o);
        o = fmaf(WO[5], a[5], o);
        const int n = n0 + k;
        if (n < NSEG) orow[n] = o;
    }
}

extern "C" void kernel_launch(void* const* d_in, const int* in_sizes, int n_in,
                              void* d_out, int out_size, void* d_ws, size_t ws_size,
                              hipStream_t stream) {
    const float* x  = (const float*)d_in[0];
    const float* w1 = (const float*)d_in[1];
    const float* b1 = (const float*)d_in[2];
    const float* w2 = (const float*)d_in[3];
    const float* b2 = (const float*)d_in[4];
    const float* wo = (const float*)d_in[5];
    float* out = (float*)d_out;
    sig_scan_kernel<<<NBATCH, TPB, 0, stream>>>(x, w1, b1, w2, b2, wo, out);
}

// Round 14
// 19.698 us; speedup vs baseline: 1.2290x; 1.0014x over previous
//
#include <hip/hip_runtime.h>

#define LPTS  2048   // points per row
#define NSEG  2047   // increments per row
#define TPB   256
#define STEPS 8      // segments per thread
#define NBATCH 2048
#define NWAVE (TPB / 64)

// DPP lane-shift returning 0 for lanes without a source (bound_ctrl) or in
// masked-off rows (row_mask). Zero == identity for all our combines.
template <int CTRL, int RMASK, bool BC>
__device__ __forceinline__ float dpp_f(float s) {
    return __int_as_float(__builtin_amdgcn_update_dpp(
        0, __float_as_int(s), CTRL, RMASK, 0xF, BC));
}

// Quotient signature state (7 floats): s[0]=a1x s[1]=a1y s[2]=a2xx s[3]=a2xy
// s[4]=a2yx s[5]=a2yy s[6]=z3 (= <WO3, a3>).

// s := s ⊗ sig(segment v); returns this step's z-increment (zeta).
__device__ __forceinline__ float chen_step7z(float s[7], float vx, float vy,
                                             const float WO[14], float WO78,
                                             float WO1112) {
    const float qxx = 0.5f * vx * vx;
    const float qxy = 0.5f * vx * vy;
    const float qyy = 0.5f * vy * vy;
    const float wx = fmaf(vx, (1.0f / 3.0f), s[0]);
    const float wy = fmaf(vy, (1.0f / 3.0f), s[1]);
    const float tvxx = fmaf(WO[7], vy, WO[6] * vx);
    const float tvxy = fmaf(WO[9], vy, WO[8] * vx);
    const float tvyx = fmaf(WO[11], vy, WO[10] * vx);
    const float tvyy = fmaf(WO[13], vy, WO[12] * vx);
    const float tqx = fmaf(WO[9], qyy, fmaf(WO78, qxy, WO[6] * qxx));
    const float tqy = fmaf(WO[13], qyy, fmaf(WO1112, qxy, WO[10] * qxx));
    float z1 = s[2] * tvxx;
    z1 = fmaf(s[4], tvyx, z1);
    z1 = fmaf(wx, tqx, z1);
    float z2 = fmaf(s[5], tvyy, s[3] * tvxy);
    z2 = fmaf(wy, tqy, z2);
    const float zeta = z1 + z2;
    s[6] += zeta;
    const float ux = fmaf(vx, 0.5f, s[0]);
    const float uy = fmaf(vy, 0.5f, s[1]);
    s[2] = fmaf(ux, vx, s[2]);
    s[3] = fmaf(ux, vy, s[3]);
    s[4] = fmaf(uy, vx, s[4]);
    s[5] = fmaf(uy, vy, s[5]);
    s[0] += vx;
    s[1] += vy;
    return zeta;
}

// Full 7-state combine (cross-wave carry stitching only).
__device__ __forceinline__ void chen_combine7(const float a[7], float b[7],
                                              const float WO[14]) {
    const float tvxx = fmaf(WO[7], b[1], WO[6] * b[0]);
    const float tvxy = fmaf(WO[9], b[1], WO[8] * b[0]);
    const float tvyx = fmaf(WO[11], b[1], WO[10] * b[0]);
    const float tvyy = fmaf(WO[13], b[1], WO[12] * b[0]);
    const float ubx = fmaf(WO[9], b[5], fmaf(WO[8], b[4], fmaf(WO[7], b[3], WO[6] * b[2])));
    const float uby = fmaf(WO[13], b[5], fmaf(WO[12], b[4], fmaf(WO[11], b[3], WO[10] * b[2])));
    float z1 = fmaf(a[2], tvxx, a[6] + b[6]);
    z1 = fmaf(a[4], tvyx, z1);
    z1 = fmaf(a[0], ubx, z1);
    float z2 = fmaf(a[5], tvyy, a[3] * tvxy);
    z2 = fmaf(a[1], uby, z2);
    const float cxx = a[2] + fmaf(a[0], b[0], b[2]);
    const float cxy = a[3] + fmaf(a[0], b[1], b[3]);
    const float cyx = a[4] + fmaf(a[1], b[0], b[4]);
    const float cyy = a[5] + fmaf(a[1], b[1], b[5]);
    b[0] = a[0] + b[0];
    b[1] = a[1] + b[1];
    b[2] = cxx;
    b[3] = cxy;
    b[4] = cyx;
    b[5] = cyy;
    b[6] = z1 + z2;
}

// Cheap 6-state combine (a1,a2 only — z deferred): b := a ⊗ b, 10 ops.
__device__ __forceinline__ void chen_combine6(const float a[6], float b[6]) {
    const float cxx = a[2] + fmaf(a[0], b[0], b[2]);
    const float cxy = a[3] + fmaf(a[0], b[1], b[3]);
    const float cyx = a[4] + fmaf(a[1], b[0], b[4]);
    const float cyy = a[5] + fmaf(a[1], b[1], b[5]);
    b[0] = a[0] + b[0];
    b[1] = a[1] + b[1];
    b[2] = cxx;
    b[3] = cxy;
    b[4] = cyx;
    b[5] = cyy;
}

// pointwise MLP 1 -> 8 -> 2 (ReLU between)
__device__ __forceinline__ void augment(float x,
                                        const float W1[8], const float B1[8],
                                        const float W2x[8], const float W2y[8],
                                        float B2x, float B2y,
                                        float& px, float& py) {
    float ox = B2x, oy = B2y;
#pragma unroll
    for (int c = 0; c < 8; ++c) {
        float h = fmaxf(fmaf(W1[c], x, B1[c]), 0.0f);
        ox = fmaf(W2x[c], h, ox);
        oy = fmaf(W2y[c], h, oy);
    }
    px = ox;
    py = oy;
}

#define SCAN6_ROUND(CTRL, RMASK, BC)                                     \
    {                                                                    \
        float p[6];                                                      \
        _Pragma("unroll")                                                \
        for (int i = 0; i < 6; ++i) p[i] = dpp_f<CTRL, RMASK, BC>(s[i]); \
        chen_combine6(p, s);                                             \
    }

#define USCAN_ROUND(CTRL, RMASK, BC) u += dpp_f<CTRL, RMASK, BC>(u);

__global__ void sig_scan_kernel(
    const float* __restrict__ x, const float* __restrict__ w1,
    const float* __restrict__ b1, const float* __restrict__ w2,
    const float* __restrict__ b2, const float* __restrict__ wout,
    float* __restrict__ out) {
    __shared__ float wsum[NWAVE][8];

    const int t = threadIdx.x;
    const int lane = t & 63;
    const int wv = t >> 6;
    const int brow = blockIdx.x;
    const float* __restrict__ xrow = x + (size_t)brow * LPTS;

    // uniform weights (uniform addresses -> s_load)
    float W1[8], B1[8], W2x[8], W2y[8];
#pragma unroll
    for (int c = 0; c < 8; ++c) {
        W1[c] = w1[c];
        B1[c] = b1[c];
        W2x[c] = w2[c];
        W2y[c] = w2[8 + c];
    }
    const float B2x = b2[0], B2y = b2[1];
    float WO[14];
#pragma unroll
    for (int i = 0; i < 14; ++i) WO[i] = wout[i];
    const float WO78 = WO[7] + WO[8];
    const float WO1112 = WO[11] + WO[12];

    // ---- phase 1: load 9 points, augment, increments, local 7-state sig ----
    const int n0 = t * STEPS;
    const float4 xa = *reinterpret_cast<const float4*>(xrow + n0);
    const float4 xb = *reinterpret_cast<const float4*>(xrow + n0 + 4);
    const int ib = (n0 + STEPS > LPTS - 1) ? (LPTS - 1) : (n0 + STEPS);
    const float x8 = xrow[ib];  // clamped -> v=0 identity for last thread
    const float xv[STEPS + 1] = {xa.x, xa.y, xa.z, xa.w,
                                 xb.x, xb.y, xb.z, xb.w, x8};

    float vx[STEPS], vy[STEPS], zeta[STEPS];
    float s[7] = {0, 0, 0, 0, 0, 0, 0};
    float ppx, ppy;
    augment(xv[0], W1, B1, W2x, W2y, B2x, B2y, ppx, ppy);
#pragma unroll
    for (int k = 0; k < STEPS; ++k) {
        float px, py;
        augment(xv[k + 1], W1, B1, W2x, W2y, B2x, B2y, px, py);
        vx[k] = px - ppx;
        vy[k] = py - ppy;
        ppx = px;
        ppy = py;
        zeta[k] = chen_step7z(s, vx[k], vy[k], WO, WO78, WO1112);
    }

    // keep local chunk sig (scan overwrites s[0..5]); s[6]=zloc never scanned
    float sl[7];
#pragma unroll
    for (int i = 0; i < 7; ++i) sl[i] = s[i];

    // ---- phase 2a: wave64 inclusive 6-state DPP scan (z deferred) ----
    SCAN6_ROUND(0x111, 0xF, true)   // row_shr:1
    SCAN6_ROUND(0x112, 0xF, true)   // row_shr:2
    SCAN6_ROUND(0x114, 0xF, true)   // row_shr:4
    SCAN6_ROUND(0x118, 0xF, true)   // row_shr:8
    SCAN6_ROUND(0x142, 0xA, false)  // row_bcast15 -> rows 1,3
    SCAN6_ROUND(0x143, 0xC, false)  // row_bcast31 -> rows 2,3

    // exclusive 6-state carry (wave_shr:1, lane 0 -> identity)
    float e[6];
#pragma unroll
    for (int i = 0; i < 6; ++i) e[i] = dpp_f<0x138, 0xF, true>(s[i]);

    // per-lane z summand: u = zloc + <WO3, e_a2 (x) s1loc> + <WO3, e_a1 (x) a2loc>
    float u;
    {
        const float tvxx = fmaf(WO[7], sl[1], WO[6] * sl[0]);
        const float tvxy = fmaf(WO[9], sl[1], WO[8] * sl[0]);
        const float tvyx = fmaf(WO[11], sl[1], WO[10] * sl[0]);
        const float tvyy = fmaf(WO[13], sl[1], WO[12] * sl[0]);
        const float ubx = fmaf(WO[9], sl[5], fmaf(WO[8], sl[4], fmaf(WO[7], sl[3], WO[6] * sl[2])));
        const float uby = fmaf(WO[13], sl[5], fmaf(WO[12], sl[4], fmaf(WO[11], sl[3], WO[10] * sl[2])));
        u = fmaf(e[2], tvxx, sl[6]);
        u = fmaf(e[3], tvxy, u);
        u = fmaf(e[4], tvyx, u);
        u = fmaf(e[5], tvyy, u);
        u = fmaf(e[0], ubx, u);
        u = fmaf(e[1], uby, u);
    }

    // inclusive add-scan of u (cheap: 1 DPP + 1 add per round)
    USCAN_ROUND(0x111, 0xF, true)
    USCAN_ROUND(0x112, 0xF, true)
    USCAN_ROUND(0x114, 0xF, true)
    USCAN_ROUND(0x118, 0xF, true)
    USCAN_ROUND(0x142, 0xA, false)
    USCAN_ROUND(0x143, 0xC, false)

    // ---- phase 2b: cross-wave combine (one barrier, broadcast reads) ----
    if (lane == 63) {
#pragma unroll
        for (int i = 0; i < 6; ++i) wsum[wv][i] = s[i];
        wsum[wv][6] = u;  // wave z total
    }
    __syncthreads();

    float a[7];  // exclusive carry (wave-local)
#pragma unroll
    for (int i = 0; i < 6; ++i) a[i] = e[i];
    a[6] = dpp_f<0x138, 0xF, true>(u);  // exclusive z prefix
    for (int w = wv - 1; w >= 0; --w) {
        float tw[7];
#pragma unroll
        for (int i = 0; i < 7; ++i) tw[i] = wsum[w][i];
        chen_combine7(tw, a, WO);
    }

    // ---- phase 3: carry-linearized replay ----
    // o_k = K0 + Kx p1x + Ky p1y + Kxx p2xx + Kxy p2xy + Kyx p2yx + Kyy p2yy + zp
    // where (p1,p2,zp) is the LOCAL prefix (zp via saved zeta increments).
    float K0 = a[6];
    K0 = fmaf(WO[0], a[0], K0);
    K0 = fmaf(WO[1], a[1], K0);
    K0 = fmaf(WO[2], a[2], K0);
    K0 = fmaf(WO[3], a[3], K0);
    K0 = fmaf(WO[4], a[4], K0);
    K0 = fmaf(WO[5], a[5], K0);
    float Kx = WO[0];
    Kx = fmaf(WO[2], a[0], Kx);
    Kx = fmaf(WO[4], a[1], Kx);
    Kx = fmaf(WO[6], a[2], Kx);
    Kx = fmaf(WO[8], a[3], Kx);
    Kx = fmaf(WO[10], a[4], Kx);
    Kx = fmaf(WO[12], a[5], Kx);
    float Ky = WO[1];
    Ky = fmaf(WO[3], a[0], Ky);
    Ky = fmaf(WO[5], a[1], Ky);
    Ky = fmaf(WO[7], a[2], Ky);
    Ky = fmaf(WO[9], a[3], Ky);
    Ky = fmaf(WO[11], a[4], Ky);
    Ky = fmaf(WO[13], a[5], Ky);
    const float Kxx = fmaf(WO[6], a[0], fmaf(WO[10], a[1], WO[2]));
    const float Kxy = fmaf(WO[7], a[0], fmaf(WO[11], a[1], WO[3]));
    const float Kyx = fmaf(WO[8], a[0], fmaf(WO[12], a[1], WO[4]));
    const float Kyy = fmaf(WO[9], a[0], fmaf(WO[13], a[1], WO[5]));

    float p1x = 0.0f, p1y = 0.0f;
    float p2xx = 0.0f, p2xy = 0.0f, p2yx = 0.0f, p2yy = 0.0f;
    float zp = 0.0f;

    float* __restrict__ orow = out + (size_t)brow * NSEG;
#pragma unroll
    for (int k = 0; k < STEPS; ++k) {
        const float vxk = vx[k], vyk = vy[k];
        const float ux = fmaf(vxk, 0.5f, p1x);
        const float uy = fmaf(vyk, 0.5f, p1y);
        p2xx = fmaf(ux, vxk, p2xx);
        p2xy = fmaf(ux, vyk, p2xy);
        p2yx = fmaf(uy, vxk, p2yx);
        p2yy = fmaf(uy, vyk, p2yy);
        p1x += vxk;
        p1y += vyk;
        zp += zeta[k];
        float o = fmaf(Kx, p1x, K0);
        o = fmaf(Ky, p1y, o);
        o = fmaf(Kxx, p2xx, o);
        o = fmaf(Kxy, p2xy, o);
        o = fmaf(Kyx, p2yx, o);
        o = fmaf(Kyy, p2yy, o);
        o += zp;
        const int n = n0 + k;
        if (n < NSEG) orow[n] = o;
    }
}

extern "C" void kernel_launch(void* const* d_in, const int* in_sizes, int n_in,
                              void* d_out, int out_size, void* d_ws, size_t ws_size,
                              hipStream_t stream) {
    const float* x  = (const float*)d_in[0];
    const float* w1 = (const float*)d_in[1];
    const float* b1 = (const float*)d_in[2];
    const float* w2 = (const float*)d_in[3];
    const float* b2 = (const float*)d_in[4];
    const float* wo = (const float*)d_in[5];
    float* out = (float*)d_out;
    sig_scan_kernel<<<NBATCH, TPB, 0, stream>>>(x, w1, b1, w2, b2, wo, out);
}

// Round 15
// 19.640 us; speedup vs baseline: 1.2326x; 1.0030x over previous
//
#include <hip/hip_runtime.h>

#define LPTS  2048   // points per row
#define NSEG  2047   // increments per row
#define TPB   256
#define STEPS 8      // segments per thread
#define NBATCH 2048
#define NWAVE (TPB / 64)

// DPP lane-shift returning 0 for lanes without a source (bound_ctrl) or in
// masked-off rows (row_mask). Zero == identity for all our combines.
template <int CTRL, int RMASK, bool BC>
__device__ __forceinline__ float dpp_f(float s) {
    return __int_as_float(__builtin_amdgcn_update_dpp(
        0, __float_as_int(s), CTRL, RMASK, 0xF, BC));
}

// Quotient signature state (7 floats): s[0]=a1x s[1]=a1y s[2]=a2xx s[3]=a2xy
// s[4]=a2yx s[5]=a2yy s[6]=z3 (= <WO3, a3>).

// s := s ⊗ sig(segment v); returns this step's z-increment (zeta).
__device__ __forceinline__ float chen_step7z(float s[7], float vx, float vy,
                                             const float WO[14], float WO78,
                                             float WO1112) {
    const float qxx = 0.5f * vx * vx;
    const float qxy = 0.5f * vx * vy;
    const float qyy = 0.5f * vy * vy;
    const float wx = fmaf(vx, (1.0f / 3.0f), s[0]);
    const float wy = fmaf(vy, (1.0f / 3.0f), s[1]);
    const float tvxx = fmaf(WO[7], vy, WO[6] * vx);
    const float tvxy = fmaf(WO[9], vy, WO[8] * vx);
    const float tvyx = fmaf(WO[11], vy, WO[10] * vx);
    const float tvyy = fmaf(WO[13], vy, WO[12] * vx);
    const float tqx = fmaf(WO[9], qyy, fmaf(WO78, qxy, WO[6] * qxx));
    const float tqy = fmaf(WO[13], qyy, fmaf(WO1112, qxy, WO[10] * qxx));
    float z1 = s[2] * tvxx;
    z1 = fmaf(s[4], tvyx, z1);
    z1 = fmaf(wx, tqx, z1);
    float z2 = fmaf(s[5], tvyy, s[3] * tvxy);
    z2 = fmaf(wy, tqy, z2);
    const float zeta = z1 + z2;
    s[6] += zeta;
    const float ux = fmaf(vx, 0.5f, s[0]);
    const float uy = fmaf(vy, 0.5f, s[1]);
    s[2] = fmaf(ux, vx, s[2]);
    s[3] = fmaf(ux, vy, s[3]);
    s[4] = fmaf(uy, vx, s[4]);
    s[5] = fmaf(uy, vy, s[5]);
    s[0] += vx;
    s[1] += vy;
    return zeta;
}

// Full 7-state combine (cross-wave carry stitching only).
__device__ __forceinline__ void chen_combine7(const float a[7], float b[7],
                                              const float WO[14]) {
    const float tvxx = fmaf(WO[7], b[1], WO[6] * b[0]);
    const float tvxy = fmaf(WO[9], b[1], WO[8] * b[0]);
    const float tvyx = fmaf(WO[11], b[1], WO[10] * b[0]);
    const float tvyy = fmaf(WO[13], b[1], WO[12] * b[0]);
    const float ubx = fmaf(WO[9], b[5], fmaf(WO[8], b[4], fmaf(WO[7], b[3], WO[6] * b[2])));
    const float uby = fmaf(WO[13], b[5], fmaf(WO[12], b[4], fmaf(WO[11], b[3], WO[10] * b[2])));
    float z1 = fmaf(a[2], tvxx, a[6] + b[6]);
    z1 = fmaf(a[4], tvyx, z1);
    z1 = fmaf(a[0], ubx, z1);
    float z2 = fmaf(a[5], tvyy, a[3] * tvxy);
    z2 = fmaf(a[1], uby, z2);
    const float cxx = a[2] + fmaf(a[0], b[0], b[2]);
    const float cxy = a[3] + fmaf(a[0], b[1], b[3]);
    const float cyx = a[4] + fmaf(a[1], b[0], b[4]);
    const float cyy = a[5] + fmaf(a[1], b[1], b[5]);
    b[0] = a[0] + b[0];
    b[1] = a[1] + b[1];
    b[2] = cxx;
    b[3] = cxy;
    b[4] = cyx;
    b[5] = cyy;
    b[6] = z1 + z2;
}

// Cheap 6-state combine (a1,a2 only — z deferred): b := a ⊗ b, 10 ops.
__device__ __forceinline__ void chen_combine6(const float a[6], float b[6]) {
    const float cxx = a[2] + fmaf(a[0], b[0], b[2]);
    const float cxy = a[3] + fmaf(a[0], b[1], b[3]);
    const float cyx = a[4] + fmaf(a[1], b[0], b[4]);
    const float cyy = a[5] + fmaf(a[1], b[1], b[5]);
    b[0] = a[0] + b[0];
    b[1] = a[1] + b[1];
    b[2] = cxx;
    b[3] = cxy;
    b[4] = cyx;
    b[5] = cyy;
}

// pointwise MLP 1 -> 8 -> 2 (ReLU between)
__device__ __forceinline__ void augment(float x,
                                        const float W1[8], const float B1[8],
                                        const float W2x[8], const float W2y[8],
                                        float B2x, float B2y,
                                        float& px, float& py) {
    float ox = B2x, oy = B2y;
#pragma unroll
    for (int c = 0; c < 8; ++c) {
        float h = fmaxf(fmaf(W1[c], x, B1[c]), 0.0f);
        ox = fmaf(W2x[c], h, ox);
        oy = fmaf(W2y[c], h, oy);
    }
    px = ox;
    py = oy;
}

#define SCAN6_ROUND(CTRL, RMASK, BC)                                     \
    {                                                                    \
        float p[6];                                                      \
        _Pragma("unroll")                                                \
        for (int i = 0; i < 6; ++i) p[i] = dpp_f<CTRL, RMASK, BC>(s[i]); \
        chen_combine6(p, s);                                             \
    }

#define USCAN_ROUND(CTRL, RMASK, BC) u += dpp_f<CTRL, RMASK, BC>(u);

__global__ void sig_scan_kernel(
    const float* __restrict__ x, const float* __restrict__ w1,
    const float* __restrict__ b1, const float* __restrict__ w2,
    const float* __restrict__ b2, const float* __restrict__ wout,
    float* __restrict__ out) {
    __shared__ float wsum[NWAVE][8];

    const int t = threadIdx.x;
    const int lane = t & 63;
    const int wv = t >> 6;
    const int brow = blockIdx.x;
    const float* __restrict__ xrow = x + (size_t)brow * LPTS;

    // uniform weights (uniform addresses -> s_load)
    float W1[8], B1[8], W2x[8], W2y[8];
#pragma unroll
    for (int c = 0; c < 8; ++c) {
        W1[c] = w1[c];
        B1[c] = b1[c];
        W2x[c] = w2[c];
        W2y[c] = w2[8 + c];
    }
    const float B2x = b2[0], B2y = b2[1];
    float WO[14];
#pragma unroll
    for (int i = 0; i < 14; ++i) WO[i] = wout[i];
    const float WO78 = WO[7] + WO[8];
    const float WO1112 = WO[11] + WO[12];

    // ---- phase 1: load 8 points + neighbor via DPP, augment, local sig ----
    const int n0 = t * STEPS;
    const float4 xa = *reinterpret_cast<const float4*>(xrow + n0);
    const float4 xb = *reinterpret_cast<const float4*>(xrow + n0 + 4);
    // xv[8] = x[n0+8] = next lane's xa.x (wave_shl:1); lane 63 loads directly.
    float x8 = dpp_f<0x130, 0xF, true>(xa.x);
    if (lane == 63) {
        const int ib = (n0 + STEPS > LPTS - 1) ? (LPTS - 1) : (n0 + STEPS);
        x8 = xrow[ib];  // clamped for t==255 -> v=0 identity segment
    }
    const float xv[STEPS + 1] = {xa.x, xa.y, xa.z, xa.w,
                                 xb.x, xb.y, xb.z, xb.w, x8};

    float vx[STEPS], vy[STEPS], zeta[STEPS];
    float s[7] = {0, 0, 0, 0, 0, 0, 0};
    float ppx, ppy;
    augment(xv[0], W1, B1, W2x, W2y, B2x, B2y, ppx, ppy);
#pragma unroll
    for (int k = 0; k < STEPS; ++k) {
        float px, py;
        augment(xv[k + 1], W1, B1, W2x, W2y, B2x, B2y, px, py);
        vx[k] = px - ppx;
        vy[k] = py - ppy;
        ppx = px;
        ppy = py;
        zeta[k] = chen_step7z(s, vx[k], vy[k], WO, WO78, WO1112);
    }

    // keep local chunk sig (scan overwrites s[0..5]); s[6]=zloc never scanned
    float sl[7];
#pragma unroll
    for (int i = 0; i < 7; ++i) sl[i] = s[i];

    // ---- phase 2a: wave64 inclusive 6-state DPP scan (z deferred) ----
    SCAN6_ROUND(0x111, 0xF, true)   // row_shr:1
    SCAN6_ROUND(0x112, 0xF, true)   // row_shr:2
    SCAN6_ROUND(0x114, 0xF, true)   // row_shr:4
    SCAN6_ROUND(0x118, 0xF, true)   // row_shr:8
    SCAN6_ROUND(0x142, 0xA, false)  // row_bcast15 -> rows 1,3
    SCAN6_ROUND(0x143, 0xC, false)  // row_bcast31 -> rows 2,3

    // exclusive 6-state carry (wave_shr:1, lane 0 -> identity)
    float e[6];
#pragma unroll
    for (int i = 0; i < 6; ++i) e[i] = dpp_f<0x138, 0xF, true>(s[i]);

    // per-lane z summand: u = zloc + <WO3, e_a2 (x) s1loc> + <WO3, e_a1 (x) a2loc>
    float u;
    {
        const float tvxx = fmaf(WO[7], sl[1], WO[6] * sl[0]);
        const float tvxy = fmaf(WO[9], sl[1], WO[8] * sl[0]);
        const float tvyx = fmaf(WO[11], sl[1], WO[10] * sl[0]);
        const float tvyy = fmaf(WO[13], sl[1], WO[12] * sl[0]);
        const float ubx = fmaf(WO[9], sl[5], fmaf(WO[8], sl[4], fmaf(WO[7], sl[3], WO[6] * sl[2])));
        const float uby = fmaf(WO[13], sl[5], fmaf(WO[12], sl[4], fmaf(WO[11], sl[3], WO[10] * sl[2])));
        u = fmaf(e[2], tvxx, sl[6]);
        u = fmaf(e[3], tvxy, u);
        u = fmaf(e[4], tvyx, u);
        u = fmaf(e[5], tvyy, u);
        u = fmaf(e[0], ubx, u);
        u = fmaf(e[1], uby, u);
    }

    // inclusive add-scan of u (cheap: 1 DPP + 1 add per round)
    USCAN_ROUND(0x111, 0xF, true)
    USCAN_ROUND(0x112, 0xF, true)
    USCAN_ROUND(0x114, 0xF, true)
    USCAN_ROUND(0x118, 0xF, true)
    USCAN_ROUND(0x142, 0xA, false)
    USCAN_ROUND(0x143, 0xC, false)

    // ---- phase 2b: cross-wave combine (one barrier, broadcast reads) ----
    if (lane == 63) {
#pragma unroll
        for (int i = 0; i < 6; ++i) wsum[wv][i] = s[i];
        wsum[wv][6] = u;  // wave z total
    }
    __syncthreads();

    float a[7];  // exclusive carry (wave-local)
#pragma unroll
    for (int i = 0; i < 6; ++i) a[i] = e[i];
    a[6] = dpp_f<0x138, 0xF, true>(u);  // exclusive z prefix
    for (int w = wv - 1; w >= 0; --w) {
        float tw[7];
#pragma unroll
        for (int i = 0; i < 7; ++i) tw[i] = wsum[w][i];
        chen_combine7(tw, a, WO);
    }

    // ---- phase 3: carry-linearized replay, batched 16B stores ----
    float K0 = a[6];
    K0 = fmaf(WO[0], a[0], K0);
    K0 = fmaf(WO[1], a[1], K0);
    K0 = fmaf(WO[2], a[2], K0);
    K0 = fmaf(WO[3], a[3], K0);
    K0 = fmaf(WO[4], a[4], K0);
    K0 = fmaf(WO[5], a[5], K0);
    float Kx = WO[0];
    Kx = fmaf(WO[2], a[0], Kx);
    Kx = fmaf(WO[4], a[1], Kx);
    Kx = fmaf(WO[6], a[2], Kx);
    Kx = fmaf(WO[8], a[3], Kx);
    Kx = fmaf(WO[10], a[4], Kx);
    Kx = fmaf(WO[12], a[5], Kx);
    float Ky = WO[1];
    Ky = fmaf(WO[3], a[0], Ky);
    Ky = fmaf(WO[5], a[1], Ky);
    Ky = fmaf(WO[7], a[2], Ky);
    Ky = fmaf(WO[9], a[3], Ky);
    Ky = fmaf(WO[11], a[4], Ky);
    Ky = fmaf(WO[13], a[5], Ky);
    const float Kxx = fmaf(WO[6], a[0], fmaf(WO[10], a[1], WO[2]));
    const float Kxy = fmaf(WO[7], a[0], fmaf(WO[11], a[1], WO[3]));
    const float Kyx = fmaf(WO[8], a[0], fmaf(WO[12], a[1], WO[4]));
    const float Kyy = fmaf(WO[9], a[0], fmaf(WO[13], a[1], WO[5]));

    float p1x = 0.0f, p1y = 0.0f;
    float p2xx = 0.0f, p2xy = 0.0f, p2yx = 0.0f, p2yy = 0.0f;
    float zp = 0.0f;
    float og[STEPS];
#pragma unroll
    for (int k = 0; k < STEPS; ++k) {
        const float vxk = vx[k], vyk = vy[k];
        const float ux = fmaf(vxk, 0.5f, p1x);
        const float uy = fmaf(vyk, 0.5f, p1y);
        p2xx = fmaf(ux, vxk, p2xx);
        p2xy = fmaf(ux, vyk, p2xy);
        p2yx = fmaf(uy, vxk, p2yx);
        p2yy = fmaf(uy, vyk, p2yy);
        p1x += vxk;
        p1y += vyk;
        zp += zeta[k];
        float o = fmaf(Kx, p1x, K0);
        o = fmaf(Ky, p1y, o);
        o = fmaf(Kxx, p2xx, o);
        o = fmaf(Kxy, p2xy, o);
        o = fmaf(Kyx, p2yx, o);
        o = fmaf(Kyy, p2yy, o);
        o += zp;
        og[k] = o;
    }

    float* __restrict__ dst = out + (size_t)brow * NSEG + n0;
    if (t != TPB - 1) {
        __builtin_memcpy(dst, &og[0], 16);       // 8 contiguous outputs ->
        __builtin_memcpy(dst + 4, &og[4], 16);   // 2 x dwordx4 stores
    } else {
        __builtin_memcpy(dst, &og[0], 16);       // tail: 2040..2043
        dst[4] = og[4];                           // 2044
        dst[5] = og[5];                           // 2045
        dst[6] = og[6];                           // 2046
    }
}

extern "C" void kernel_launch(void* const* d_in, const int* in_sizes, int n_in,
                              void* d_out, int out_size, void* d_ws, size_t ws_size,
                              hipStream_t stream) {
    const float* x  = (const float*)d_in[0];
    const float* w1 = (const float*)d_in[1];
    const float* b1 = (const float*)d_in[2];
    const float* w2 = (const float*)d_in[3];
    const float* b2 = (const float*)d_in[4];
    const float* wo = (const float*)d_in[5];
    float* out = (float*)d_out;
    sig_scan_kernel<<<NBATCH, TPB, 0, stream>>>(x, w1, b1, w2, b2, wo, out);
}

// Round 16
// 19.518 us; speedup vs baseline: 1.2403x; 1.0062x over previous
//
#include <hip/hip_runtime.h>

#define LPTS  2048   // points per row
#define NSEG  2047   // increments per row
#define TPB   256
#define STEPS 8      // segments per thread
#define NBATCH 2048
#define NWAVE (TPB / 64)

// DPP lane-shift returning 0 for lanes without a source (bound_ctrl) or in
// masked-off rows (row_mask). Zero == identity for all our combines.
template <int CTRL, int RMASK, bool BC>
__device__ __forceinline__ float dpp_f(float s) {
    return __int_as_float(__builtin_amdgcn_update_dpp(
        0, __float_as_int(s), CTRL, RMASK, 0xF, BC));
}

// Quotient signature state (7 floats): s[0]=a1x s[1]=a1y s[2]=a2xx s[3]=a2xy
// s[4]=a2yx s[5]=a2yy s[6]=z3 (= <WO3, a3>).

// s := s ⊗ sig(segment v); returns this step's z-increment (zeta).
__device__ __forceinline__ float chen_step7z(float s[7], float vx, float vy,
                                             const float WO[14], float WO78,
                                             float WO1112) {
    const float qxx = 0.5f * vx * vx;
    const float qxy = 0.5f * vx * vy;
    const float qyy = 0.5f * vy * vy;
    const float wx = fmaf(vx, (1.0f / 3.0f), s[0]);
    const float wy = fmaf(vy, (1.0f / 3.0f), s[1]);
    const float tvxx = fmaf(WO[7], vy, WO[6] * vx);
    const float tvxy = fmaf(WO[9], vy, WO[8] * vx);
    const float tvyx = fmaf(WO[11], vy, WO[10] * vx);
    const float tvyy = fmaf(WO[13], vy, WO[12] * vx);
    const float tqx = fmaf(WO[9], qyy, fmaf(WO78, qxy, WO[6] * qxx));
    const float tqy = fmaf(WO[13], qyy, fmaf(WO1112, qxy, WO[10] * qxx));
    float z1 = s[2] * tvxx;
    z1 = fmaf(s[4], tvyx, z1);
    z1 = fmaf(wx, tqx, z1);
    float z2 = fmaf(s[5], tvyy, s[3] * tvxy);
    z2 = fmaf(wy, tqy, z2);
    const float zeta = z1 + z2;
    s[6] += zeta;
    const float ux = fmaf(vx, 0.5f, s[0]);
    const float uy = fmaf(vy, 0.5f, s[1]);
    s[2] = fmaf(ux, vx, s[2]);
    s[3] = fmaf(ux, vy, s[3]);
    s[4] = fmaf(uy, vx, s[4]);
    s[5] = fmaf(uy, vy, s[5]);
    s[0] += vx;
    s[1] += vy;
    return zeta;
}

// Full 7-state combine (cross-wave carry stitching only).
__device__ __forceinline__ void chen_combine7(const float a[7], float b[7],
                                              const float WO[14]) {
    const float tvxx = fmaf(WO[7], b[1], WO[6] * b[0]);
    const float tvxy = fmaf(WO[9], b[1], WO[8] * b[0]);
    const float tvyx = fmaf(WO[11], b[1], WO[10] * b[0]);
    const float tvyy = fmaf(WO[13], b[1], WO[12] * b[0]);
    const float ubx = fmaf(WO[9], b[5], fmaf(WO[8], b[4], fmaf(WO[7], b[3], WO[6] * b[2])));
    const float uby = fmaf(WO[13], b[5], fmaf(WO[12], b[4], fmaf(WO[11], b[3], WO[10] * b[2])));
    float z1 = fmaf(a[2], tvxx, a[6] + b[6]);
    z1 = fmaf(a[4], tvyx, z1);
    z1 = fmaf(a[0], ubx, z1);
    float z2 = fmaf(a[5], tvyy, a[3] * tvxy);
    z2 = fmaf(a[1], uby, z2);
    const float cxx = a[2] + fmaf(a[0], b[0], b[2]);
    const float cxy = a[3] + fmaf(a[0], b[1], b[3]);
    const float cyx = a[4] + fmaf(a[1], b[0], b[4]);
    const float cyy = a[5] + fmaf(a[1], b[1], b[5]);
    b[0] = a[0] + b[0];
    b[1] = a[1] + b[1];
    b[2] = cxx;
    b[3] = cxy;
    b[4] = cyx;
    b[5] = cyy;
    b[6] = z1 + z2;
}

// Cheap 6-state combine (a1,a2 only — z deferred): b := a ⊗ b, 10 ops.
__device__ __forceinline__ void chen_combine6(const float a[6], float b[6]) {
    const float cxx = a[2] + fmaf(a[0], b[0], b[2]);
    const float cxy = a[3] + fmaf(a[0], b[1], b[3]);
    const float cyx = a[4] + fmaf(a[1], b[0], b[4]);
    const float cyy = a[5] + fmaf(a[1], b[1], b[5]);
    b[0] = a[0] + b[0];
    b[1] = a[1] + b[1];
    b[2] = cxx;
    b[3] = cxy;
    b[4] = cyx;
    b[5] = cyy;
}

// pointwise MLP 1 -> 8 -> 2 (ReLU between)
__device__ __forceinline__ void augment(float x,
                                        const float W1[8], const float B1[8],
                                        const float W2x[8], const float W2y[8],
                                        float B2x, float B2y,
                                        float& px, float& py) {
    float ox = B2x, oy = B2y;
#pragma unroll
    for (int c = 0; c < 8; ++c) {
        float h = fmaxf(fmaf(W1[c], x, B1[c]), 0.0f);
        ox = fmaf(W2x[c], h, ox);
        oy = fmaf(W2y[c], h, oy);
    }
    px = ox;
    py = oy;
}

#define SCAN6_ROUND(CTRL, RMASK, BC)                                     \
    {                                                                    \
        float p[6];                                                      \
        _Pragma("unroll")                                                \
        for (int i = 0; i < 6; ++i) p[i] = dpp_f<CTRL, RMASK, BC>(s[i]); \
        chen_combine6(p, s);                                             \
    }

#define USCAN_ROUND(CTRL, RMASK, BC) u += dpp_f<CTRL, RMASK, BC>(u);

__global__ __launch_bounds__(TPB, 4) void sig_scan_kernel(
    const float* __restrict__ x, const float* __restrict__ w1,
    const float* __restrict__ b1, const float* __restrict__ w2,
    const float* __restrict__ b2, const float* __restrict__ wout,
    float* __restrict__ out) {
    __shared__ float wsum[NWAVE][8];

    const int t = threadIdx.x;
    const int lane = t & 63;
    const int wv = t >> 6;
    const int brow = blockIdx.x;
    const float* __restrict__ xrow = x + (size_t)brow * LPTS;

    // uniform weights (uniform addresses -> s_load)
    float W1[8], B1[8], W2x[8], W2y[8];
#pragma unroll
    for (int c = 0; c < 8; ++c) {
        W1[c] = w1[c];
        B1[c] = b1[c];
        W2x[c] = w2[c];
        W2y[c] = w2[8 + c];
    }
    const float B2x = b2[0], B2y = b2[1];
    float WO[14];
#pragma unroll
    for (int i = 0; i < 14; ++i) WO[i] = wout[i];
    const float WO78 = WO[7] + WO[8];
    const float WO1112 = WO[11] + WO[12];

    // ---- phase 1: load 8 points + neighbor via DPP, augment, local sig ----
    const int n0 = t * STEPS;
    const float4 xa = *reinterpret_cast<const float4*>(xrow + n0);
    const float4 xb = *reinterpret_cast<const float4*>(xrow + n0 + 4);
    // xv[8] = x[n0+8] = next lane's xa.x (wave_shl:1); lane 63 loads directly.
    float x8 = dpp_f<0x130, 0xF, true>(xa.x);
    if (lane == 63) {
        const int ib = (n0 + STEPS > LPTS - 1) ? (LPTS - 1) : (n0 + STEPS);
        x8 = xrow[ib];  // clamped for t==255 -> v=0 identity segment
    }
    const float xv[STEPS + 1] = {xa.x, xa.y, xa.z, xa.w,
                                 xb.x, xb.y, xb.z, xb.w, x8};

    float vx[STEPS], vy[STEPS], zeta[STEPS];
    float s[7] = {0, 0, 0, 0, 0, 0, 0};
    float ppx, ppy;
    augment(xv[0], W1, B1, W2x, W2y, B2x, B2y, ppx, ppy);
#pragma unroll
    for (int k = 0; k < STEPS; ++k) {
        float px, py;
        augment(xv[k + 1], W1, B1, W2x, W2y, B2x, B2y, px, py);
        vx[k] = px - ppx;
        vy[k] = py - ppy;
        ppx = px;
        ppy = py;
        zeta[k] = chen_step7z(s, vx[k], vy[k], WO, WO78, WO1112);
    }

    // keep local chunk sig (scan overwrites s[0..5]); s[6]=zloc never scanned
    float sl[7];
#pragma unroll
    for (int i = 0; i < 7; ++i) sl[i] = s[i];

    // ---- phase 2a: wave64 inclusive 6-state DPP scan (z deferred) ----
    SCAN6_ROUND(0x111, 0xF, true)   // row_shr:1
    SCAN6_ROUND(0x112, 0xF, true)   // row_shr:2
    SCAN6_ROUND(0x114, 0xF, true)   // row_shr:4
    SCAN6_ROUND(0x118, 0xF, true)   // row_shr:8
    SCAN6_ROUND(0x142, 0xA, false)  // row_bcast15 -> rows 1,3
    SCAN6_ROUND(0x143, 0xC, false)  // row_bcast31 -> rows 2,3

    // exclusive 6-state carry (wave_shr:1, lane 0 -> identity)
    float e[6];
#pragma unroll
    for (int i = 0; i < 6; ++i) e[i] = dpp_f<0x138, 0xF, true>(s[i]);

    // per-lane z summand: u = zloc + <WO3, e_a2 (x) s1loc> + <WO3, e_a1 (x) a2loc>
    float u;
    {
        const float tvxx = fmaf(WO[7], sl[1], WO[6] * sl[0]);
        const float tvxy = fmaf(WO[9], sl[1], WO[8] * sl[0]);
        const float tvyx = fmaf(WO[11], sl[1], WO[10] * sl[0]);
        const float tvyy = fmaf(WO[13], sl[1], WO[12] * sl[0]);
        const float ubx = fmaf(WO[9], sl[5], fmaf(WO[8], sl[4], fmaf(WO[7], sl[3], WO[6] * sl[2])));
        const float uby = fmaf(WO[13], sl[5], fmaf(WO[12], sl[4], fmaf(WO[11], sl[3], WO[10] * sl[2])));
        u = fmaf(e[2], tvxx, sl[6]);
        u = fmaf(e[3], tvxy, u);
        u = fmaf(e[4], tvyx, u);
        u = fmaf(e[5], tvyy, u);
        u = fmaf(e[0], ubx, u);
        u = fmaf(e[1], uby, u);
    }

    // inclusive add-scan of u (cheap: 1 DPP + 1 add per round)
    USCAN_ROUND(0x111, 0xF, true)
    USCAN_ROUND(0x112, 0xF, true)
    USCAN_ROUND(0x114, 0xF, true)
    USCAN_ROUND(0x118, 0xF, true)
    USCAN_ROUND(0x142, 0xA, false)
    USCAN_ROUND(0x143, 0xC, false)

    // ---- phase 2b: cross-wave combine (one barrier, broadcast reads) ----
    if (lane == 63) {
#pragma unroll
        for (int i = 0; i < 6; ++i) wsum[wv][i] = s[i];
        wsum[wv][6] = u;  // wave z total
    }
    __syncthreads();

    float a[7];  // exclusive carry (wave-local)
#pragma unroll
    for (int i = 0; i < 6; ++i) a[i] = e[i];
    a[6] = dpp_f<0x138, 0xF, true>(u);  // exclusive z prefix
    for (int w = wv - 1; w >= 0; --w) {
        float tw[7];
#pragma unroll
        for (int i = 0; i < 7; ++i) tw[i] = wsum[w][i];
        chen_combine7(tw, a, WO);
    }

    // ---- phase 3: carry-linearized replay, batched 16B stores ----
    float K0 = a[6];
    K0 = fmaf(WO[0], a[0], K0);
    K0 = fmaf(WO[1], a[1], K0);
    K0 = fmaf(WO[2], a[2], K0);
    K0 = fmaf(WO[3], a[3], K0);
    K0 = fmaf(WO[4], a[4], K0);
    K0 = fmaf(WO[5], a[5], K0);
    float Kx = WO[0];
    Kx = fmaf(WO[2], a[0], Kx);
    Kx = fmaf(WO[4], a[1], Kx);
    Kx = fmaf(WO[6], a[2], Kx);
    Kx = fmaf(WO[8], a[3], Kx);
    Kx = fmaf(WO[10], a[4], Kx);
    Kx = fmaf(WO[12], a[5], Kx);
    float Ky = WO[1];
    Ky = fmaf(WO[3], a[0], Ky);
    Ky = fmaf(WO[5], a[1], Ky);
    Ky = fmaf(WO[7], a[2], Ky);
    Ky = fmaf(WO[9], a[3], Ky);
    Ky = fmaf(WO[11], a[4], Ky);
    Ky = fmaf(WO[13], a[5], Ky);
    const float Kxx = fmaf(WO[6], a[0], fmaf(WO[10], a[1], WO[2]));
    const float Kxy = fmaf(WO[7], a[0], fmaf(WO[11], a[1], WO[3]));
    const float Kyx = fmaf(WO[8], a[0], fmaf(WO[12], a[1], WO[4]));
    const float Kyy = fmaf(WO[9], a[0], fmaf(WO[13], a[1], WO[5]));

    float p1x = 0.0f, p1y = 0.0f;
    float p2xx = 0.0f, p2xy = 0.0f, p2yx = 0.0f, p2yy = 0.0f;
    float zp = 0.0f;
    float og[STEPS];
#pragma unroll
    for (int k = 0; k < STEPS; ++k) {
        const float vxk = vx[k], vyk = vy[k];
        const float ux = fmaf(vxk, 0.5f, p1x);
        const float uy = fmaf(vyk, 0.5f, p1y);
        p2xx = fmaf(ux, vxk, p2xx);
        p2xy = fmaf(ux, vyk, p2xy);
        p2yx = fmaf(uy, vxk, p2yx);
        p2yy = fmaf(uy, vyk, p2yy);
        p1x += vxk;
        p1y += vyk;
        zp += zeta[k];
        float o = fmaf(Kx, p1x, K0);
        o = fmaf(Ky, p1y, o);
        o = fmaf(Kxx, p2xx, o);
        o = fmaf(Kxy, p2xy, o);
        o = fmaf(Kyx, p2yx, o);
        o = fmaf(Kyy, p2yy, o);
        o += zp;
        og[k] = o;
    }

    float* __restrict__ dst = out + (size_t)brow * NSEG + n0;
    if (t != TPB - 1) {
        __builtin_memcpy(dst, &og[0], 16);       // 8 contiguous outputs ->
        __builtin_memcpy(dst + 4, &og[4], 16);   // 2 x dwordx4 stores
    } else {
        __builtin_memcpy(dst, &og[0], 16);       // tail: 2040..2043
        dst[4] = og[4];                           // 2044
        dst[5] = og[5];                           // 2045
        dst[6] = og[6];                           // 2046
    }
}

extern "C" void kernel_launch(void* const* d_in, const int* in_sizes, int n_in,
                              void* d_out, int out_size, void* d_ws, size_t ws_size,
                              hipStream_t stream) {
    const float* x  = (const float*)d_in[0];
    const float* w1 = (const float*)d_in[1];
    const float* b1 = (const float*)d_in[2];
    const float* w2 = (const float*)d_in[3];
    const float* b2 = (const float*)d_in[4];
    const float* wo = (const float*)d_in[5];
    float* out = (float*)d_out;
    sig_scan_kernel<<<NBATCH, TPB, 0, stream>>>(x, w1, b1, w2, b2, wo, out);
}